// Round 8
// baseline (272.321 us; speedup 1.0000x reference)
//
#include <hip/hip_runtime.h>
#include <hip/hip_bf16.h>
#include <hip/hip_cooperative_groups.h>
#include <math.h>

namespace cg = cooperative_groups;

#define B_SZ    8
#define T_LEN   4096
#define DIN     256
#define DOUT    256
#define NST     512
#define M_ROWS  (B_SZ * T_LEN)   // 32768
#define N1      (2 * NST)        // 1024: cols [0,512)=real plane, [512,1024)=imag plane
#define K2      (N1 + DIN)       // 1280
#define CHL     64               // scan chunk length (was 128)
#define NCH     (T_LEN / CHL)    // 64

typedef __attribute__((ext_vector_type(8))) short bf16x8;
typedef __attribute__((ext_vector_type(4))) float f32x4;
typedef __hip_bfloat16 bf16;

// ws byte offsets
#define OFF_UBF  67108864
#define OFF_WP   83886080
#define OFF_W2   84410368
#define OFF_LAM  85065728
#define OFF_LAML 85069824
#define OFF_SSUM 85073920   // [B][NCH][N1] fp32 = 2 MB (uses old Ssum+Pcar space)

__device__ __forceinline__ void gl_lds16(const bf16* g, bf16* l) {
    __builtin_amdgcn_global_load_lds(
        (const __attribute__((address_space(1))) void*)g,
        (__attribute__((address_space(3))) void*)l, 16, 0, 0);
}

// ---- prep: conv_u + pack_w1 + pack_w2, split-plane (lamL = lambda^64 now) ----
__global__ __launch_bounds__(256) void prep(const float* __restrict__ u,
        const float* __restrict__ nu_log, const float* __restrict__ theta_log,
        const float* __restrict__ gamma_log,
        const float* __restrict__ B_real, const float* __restrict__ B_imag,
        const float* __restrict__ C_real, const float* __restrict__ C_imag,
        const float* __restrict__ Dm,
        bf16* __restrict__ ub, bf16* __restrict__ Wp, bf16* __restrict__ W2,
        float* __restrict__ lam, float* __restrict__ lamL) {
    int bid = blockIdx.x, tid = threadIdx.x;
    if (bid < 8192) {                       // u -> bf16
        int i = bid * 256 + tid;
        float4 v = ((const float4*)u)[i];
        union { bf16 h[4]; uint2 u2; } p;
        p.h[0] = __float2bfloat16(v.x); p.h[1] = __float2bfloat16(v.y);
        p.h[2] = __float2bfloat16(v.z); p.h[3] = __float2bfloat16(v.w);
        ((uint2*)ub)[i] = p.u2;
    } else if (bid < 9216) {                // Wp (split planes) + lam/lamL
        int c = bid - 8192;                 // 0..1023
        int n = c & (NST - 1);
        float g = expf(gamma_log[n]);
        const float* src = (c < NST) ? (B_real + (size_t)n * DIN)
                                     : (B_imag + (size_t)n * DIN);
        Wp[(size_t)c * DIN + tid] = __float2bfloat16(g * src[tid]);
        int idx = c * 256 + tid;
        if (idx < NST) {
            float lm = expf(-expf(nu_log[idx]));
            float th = expf(theta_log[idx]);
            float lr = lm * cosf(th), li = lm * sinf(th);
            lam[idx] = lr; lam[NST + idx] = li;
            float ar = lr, ai = li;
#pragma unroll
            for (int q = 0; q < 6; ++q) {   // lambda^64 (CHL=64)
                float nr = ar * ar - ai * ai;
                float ni = 2.f * ar * ai;
                ar = nr; ai = ni;
            }
            lamL[idx] = ar; lamL[NST + idx] = ai;
        }
    } else {                                // W2 = [2Cr | -2Ci | D] split
        int idx = (bid - 9216) * 256 + tid;
        if (idx < DOUT * K2) {
            int o = idx / K2, c = idx - o * K2;
            float v;
            if (c < NST)            v =  2.0f * C_real[(size_t)o * NST + c];
            else if (c < 2 * NST)   v = -2.0f * C_imag[(size_t)o * NST + (c - NST)];
            else                    v =  Dm[(size_t)o * DIN + (c - 2 * NST)];
            W2[idx] = __float2bfloat16(v);
        }
    }
}

// ---- GEMM1 (R7 verbatim): LDS-packed coalesced Bu stores ----
__global__ __launch_bounds__(256) void gemm1(const bf16* __restrict__ u,
                                             const bf16* __restrict__ Wp,
                                             bf16* __restrict__ Bu) {
    __shared__ bf16 As[128 * 32];
    __shared__ bf16 Bs[128 * 32];
    __shared__ bf16 Cs[128 * 136];
    const int tid = threadIdx.x;
    const int m0 = blockIdx.x * 128, n0 = blockIdx.y * 128;
    const int lane = tid & 63, w = tid >> 6;
    const int wm = (w >> 1) * 64, wn = (w & 1) * 64;
    const int lr16 = lane & 15, kq = (lane >> 4) * 8;
    const int srow = tid >> 2, scol = (tid & 3) * 8;

    f32x4 acc[4][4] = {};
    for (int k0 = 0; k0 < DIN; k0 += 32) {
        gl_lds16(u  + (size_t)(m0 + srow) * DIN + k0 + scol,       &As[tid * 8]);
        gl_lds16(u  + (size_t)(m0 + 64 + srow) * DIN + k0 + scol,  &As[2048 + tid * 8]);
        gl_lds16(Wp + (size_t)(n0 + srow) * DIN + k0 + scol,       &Bs[tid * 8]);
        gl_lds16(Wp + (size_t)(n0 + 64 + srow) * DIN + k0 + scol,  &Bs[2048 + tid * 8]);
        __syncthreads();
        bf16x8 af[4], bfr[4];
#pragma unroll
        for (int i = 0; i < 4; ++i)
            af[i] = *(const bf16x8*)(&As[(wm + i * 16 + lr16) * 32 + kq]);
#pragma unroll
        for (int j = 0; j < 4; ++j)
            bfr[j] = *(const bf16x8*)(&Bs[(wn + j * 16 + lr16) * 32 + kq]);
#pragma unroll
        for (int i = 0; i < 4; ++i)
#pragma unroll
            for (int j = 0; j < 4; ++j)
                acc[i][j] = __builtin_amdgcn_mfma_f32_16x16x32_bf16(af[i], bfr[j], acc[i][j], 0, 0, 0);
        __syncthreads();
    }
    const int crow = (lane >> 4) * 4, ccol = lane & 15;
#pragma unroll
    for (int i = 0; i < 4; ++i)
#pragma unroll
        for (int j = 0; j < 4; ++j)
#pragma unroll
            for (int r = 0; r < 4; ++r)
                Cs[(wm + i * 16 + crow + r) * 136 + wn + j * 16 + ccol] =
                    __float2bfloat16(acc[i][j][r]);
    __syncthreads();
#pragma unroll
    for (int p = 0; p < 8; ++p) {
        int row = p * 16 + (tid >> 4);
        int colg = (tid & 15) * 8;
        *(uint4*)(&Bu[(size_t)(m0 + row) * N1 + n0 + colg]) =
            *(const uint4*)(&Cs[row * 136 + colg]);
    }
}

// ---- fused scan (cooperative): phase A = chunk summaries, grid.sync,
//      phase B = inline exclusive carry + apply + in-place X write.
// Reads Bu written by the PREVIOUS kernel only (the proven-safe pattern).
__global__ __launch_bounds__(512) void scan_fused(bf16* __restrict__ Bu,
                                                  const float* __restrict__ lam,
                                                  const float* __restrict__ lamL,
                                                  float* __restrict__ Ssum) {
    cg::grid_group grid = cg::this_grid();
    int n = threadIdx.x, c = blockIdx.x, b = blockIdx.y;
    float lr = lam[n], li = lam[NST + n];
    bf16* base = Bu + ((size_t)b * T_LEN + (size_t)c * CHL) * N1;
    // phase A: local chunk summary
    {
        float sr = 0.f, si = 0.f;
        for (int j = 0; j < CHL; ++j) {
            float br = __bfloat162float(base[(size_t)j * N1 + n]);
            float bi = __bfloat162float(base[(size_t)j * N1 + NST + n]);
            float tr = lr * sr - li * si + br;
            float ti = lr * si + li * sr + bi;
            sr = tr; si = ti;
        }
        size_t o = ((size_t)b * NCH + c) * N1 + n;
        Ssum[o] = sr; Ssum[o + NST] = si;
    }
    grid.sync();
    // phase B: exclusive carry over earlier chunks (L2-resident Ssum)
    float Lr = lamL[n], Li = lamL[NST + n];
    float pr = 0.f, pi = 0.f;
    for (int cp = 0; cp < c; ++cp) {
        size_t o = ((size_t)b * NCH + cp) * N1 + n;
        float sr = Ssum[o], si = Ssum[o + NST];
        float tr = Lr * pr - Li * pi + sr;
        float ti = Lr * pi + Li * pr + si;
        pr = tr; pi = ti;
    }
    // apply + in-place write (chunk is L2/L3-hot from phase A)
    float xr = pr, xi = pi;
    for (int j = 0; j < CHL; ++j) {
        float br = __bfloat162float(base[(size_t)j * N1 + n]);
        float bi = __bfloat162float(base[(size_t)j * N1 + NST + n]);
        float tr = lr * xr - li * xi + br;
        float ti = lr * xi + li * xr + bi;
        xr = tr; xi = ti;
        base[(size_t)j * N1 + n]       = __float2bfloat16(xr);
        base[(size_t)j * N1 + NST + n] = __float2bfloat16(xi);
    }
}

// ---- GEMM2 (R7 verbatim): y = [X | u_bf] @ W2^T, 512 threads / 8 waves ----
__global__ __launch_bounds__(512) void gemm2(const bf16* __restrict__ X,
                                             const bf16* __restrict__ u,
                                             const bf16* __restrict__ W2,
                                             float* __restrict__ y) {
    __shared__ bf16 As[128 * 32];
    __shared__ bf16 Bs[128 * 32];
    const int tid = threadIdx.x;
    const int m0 = blockIdx.x * 128, n0 = blockIdx.y * 128;
    const int lane = tid & 63, w = tid >> 6;
    const int wm = (w >> 2) * 64, wn = (w & 3) * 32;
    const int lr16 = lane & 15, kq = (lane >> 4) * 8;
    const int srow = tid >> 2, scol = (tid & 3) * 8;

    f32x4 acc[4][2] = {};
    for (int k0 = 0; k0 < K2; k0 += 32) {
        const bf16* Asrc; size_t lda; int kc;
        if (k0 < N1) { Asrc = X; lda = N1;  kc = k0; }
        else         { Asrc = u; lda = DIN; kc = k0 - N1; }
        gl_lds16(Asrc + (size_t)(m0 + srow) * lda + kc + scol, &As[tid * 8]);
        gl_lds16(W2 + (size_t)(n0 + srow) * K2 + k0 + scol,    &Bs[tid * 8]);
        __syncthreads();
        bf16x8 af[4], bfr[2];
#pragma unroll
        for (int i = 0; i < 4; ++i)
            af[i] = *(const bf16x8*)(&As[(wm + i * 16 + lr16) * 32 + kq]);
#pragma unroll
        for (int j = 0; j < 2; ++j)
            bfr[j] = *(const bf16x8*)(&Bs[(wn + j * 16 + lr16) * 32 + kq]);
#pragma unroll
        for (int i = 0; i < 4; ++i)
#pragma unroll
            for (int j = 0; j < 2; ++j)
                acc[i][j] = __builtin_amdgcn_mfma_f32_16x16x32_bf16(af[i], bfr[j], acc[i][j], 0, 0, 0);
        __syncthreads();
    }
    const int crow = (lane >> 4) * 4, ccol = lane & 15;
#pragma unroll
    for (int i = 0; i < 4; ++i)
#pragma unroll
        for (int j = 0; j < 2; ++j)
#pragma unroll
            for (int r = 0; r < 4; ++r)
                y[(size_t)(m0 + wm + i * 16 + crow + r) * DOUT + n0 + wn + j * 16 + ccol] = acc[i][j][r];
}

extern "C" void kernel_launch(void* const* d_in, const int* in_sizes, int n_in,
                              void* d_out, int out_size, void* d_ws, size_t ws_size,
                              hipStream_t stream) {
    const float* u_in      = (const float*)d_in[0];
    const float* nu_log    = (const float*)d_in[1];
    const float* theta_log = (const float*)d_in[2];
    const float* gamma_log = (const float*)d_in[3];
    const float* B_real    = (const float*)d_in[4];
    const float* B_imag    = (const float*)d_in[5];
    const float* C_real    = (const float*)d_in[6];
    const float* C_imag    = (const float*)d_in[7];
    const float* Dm        = (const float*)d_in[8];
    float* y = (float*)d_out;
    char* ws = (char*)d_ws;

    bf16*  Bu   = (bf16*)ws;
    bf16*  u_bf = (bf16*)(ws + OFF_UBF);
    bf16*  Wp   = (bf16*)(ws + OFF_WP);
    bf16*  W2   = (bf16*)(ws + OFF_W2);
    float* lam  = (float*)(ws + OFF_LAM);
    float* lamL = (float*)(ws + OFF_LAML);
    float* Ssum = (float*)(ws + OFF_SSUM);

    prep<<<10496, 256, 0, stream>>>(u_in, nu_log, theta_log, gamma_log,
                                    B_real, B_imag, C_real, C_imag, Dm,
                                    u_bf, Wp, W2, lam, lamL);
    gemm1<<<dim3(M_ROWS / 128, N1 / 128), 256, 0, stream>>>(u_bf, Wp, Bu);
    {
        void* args[] = { (void*)&Bu, (void*)&lam, (void*)&lamL, (void*)&Ssum };
        hipLaunchCooperativeKernel((void*)scan_fused, dim3(NCH, B_SZ), dim3(512),
                                   args, 0, stream);
    }
    gemm2<<<dim3(M_ROWS / 128, DOUT / 128), 512, 0, stream>>>(Bu, u_bf, W2, y);
}

// Round 9
// 206.544 us; speedup vs baseline: 1.3185x; 1.3185x over previous
//
#include <hip/hip_runtime.h>
#include <hip/hip_bf16.h>
#include <math.h>

#define B_SZ    8
#define T_LEN   4096
#define DIN     256
#define DOUT    256
#define NST     512
#define M_ROWS  (B_SZ * T_LEN)   // 32768
#define N1      (2 * NST)        // 1024: cols [0,512)=real plane, [512,1024)=imag plane
#define K2      (N1 + DIN)       // 1280
#define CHL     128              // scan chunk length
#define NCH     (T_LEN / CHL)    // 32

typedef __attribute__((ext_vector_type(8))) short bf16x8;
typedef __attribute__((ext_vector_type(4))) float f32x4;
typedef __hip_bfloat16 bf16;

// ws byte offsets
#define OFF_UBF  67108864
#define OFF_WP   83886080
#define OFF_W2   84410368
#define OFF_LAM  85065728
#define OFF_LAML 85069824
#define OFF_SSUM 85073920

__device__ __forceinline__ void gl_lds16(const bf16* g, bf16* l) {
    __builtin_amdgcn_global_load_lds(
        (const __attribute__((address_space(1))) void*)g,
        (__attribute__((address_space(3))) void*)l, 16, 0, 0);
}

// ---- prep (R7 verbatim): conv_u + pack_w1 + pack_w2, split-plane ----
__global__ __launch_bounds__(256) void prep(const float* __restrict__ u,
        const float* __restrict__ nu_log, const float* __restrict__ theta_log,
        const float* __restrict__ gamma_log,
        const float* __restrict__ B_real, const float* __restrict__ B_imag,
        const float* __restrict__ C_real, const float* __restrict__ C_imag,
        const float* __restrict__ Dm,
        bf16* __restrict__ ub, bf16* __restrict__ Wp, bf16* __restrict__ W2,
        float* __restrict__ lam, float* __restrict__ lamL) {
    int bid = blockIdx.x, tid = threadIdx.x;
    if (bid < 8192) {                       // u -> bf16
        int i = bid * 256 + tid;
        float4 v = ((const float4*)u)[i];
        union { bf16 h[4]; uint2 u2; } p;
        p.h[0] = __float2bfloat16(v.x); p.h[1] = __float2bfloat16(v.y);
        p.h[2] = __float2bfloat16(v.z); p.h[3] = __float2bfloat16(v.w);
        ((uint2*)ub)[i] = p.u2;
    } else if (bid < 9216) {                // Wp (split planes) + lam/lamL
        int c = bid - 8192;                 // 0..1023
        int n = c & (NST - 1);
        float g = expf(gamma_log[n]);
        const float* src = (c < NST) ? (B_real + (size_t)n * DIN)
                                     : (B_imag + (size_t)n * DIN);
        Wp[(size_t)c * DIN + tid] = __float2bfloat16(g * src[tid]);
        int idx = c * 256 + tid;
        if (idx < NST) {
            float lm = expf(-expf(nu_log[idx]));
            float th = expf(theta_log[idx]);
            float lr = lm * cosf(th), li = lm * sinf(th);
            lam[idx] = lr; lam[NST + idx] = li;
            float ar = lr, ai = li;
#pragma unroll
            for (int q = 0; q < 7; ++q) {   // lambda^128 (CHL=128)
                float nr = ar * ar - ai * ai;
                float ni = 2.f * ar * ai;
                ar = nr; ai = ni;
            }
            lamL[idx] = ar; lamL[NST + idx] = ai;
        }
    } else {                                // W2 = [2Cr | -2Ci | D] split
        int idx = (bid - 9216) * 256 + tid;
        if (idx < DOUT * K2) {
            int o = idx / K2, c = idx - o * K2;
            float v;
            if (c < NST)            v =  2.0f * C_real[(size_t)o * NST + c];
            else if (c < 2 * NST)   v = -2.0f * C_imag[(size_t)o * NST + (c - NST)];
            else                    v =  Dm[(size_t)o * DIN + (c - 2 * NST)];
            W2[idx] = __float2bfloat16(v);
        }
    }
}

// ---- GEMM1 (R7 verbatim): LDS-packed coalesced Bu stores ----
__global__ __launch_bounds__(256) void gemm1(const bf16* __restrict__ u,
                                             const bf16* __restrict__ Wp,
                                             bf16* __restrict__ Bu) {
    __shared__ bf16 As[128 * 32];
    __shared__ bf16 Bs[128 * 32];
    __shared__ bf16 Cs[128 * 136];
    const int tid = threadIdx.x;
    const int m0 = blockIdx.x * 128, n0 = blockIdx.y * 128;
    const int lane = tid & 63, w = tid >> 6;
    const int wm = (w >> 1) * 64, wn = (w & 1) * 64;
    const int lr16 = lane & 15, kq = (lane >> 4) * 8;
    const int srow = tid >> 2, scol = (tid & 3) * 8;

    f32x4 acc[4][4] = {};
    for (int k0 = 0; k0 < DIN; k0 += 32) {
        gl_lds16(u  + (size_t)(m0 + srow) * DIN + k0 + scol,       &As[tid * 8]);
        gl_lds16(u  + (size_t)(m0 + 64 + srow) * DIN + k0 + scol,  &As[2048 + tid * 8]);
        gl_lds16(Wp + (size_t)(n0 + srow) * DIN + k0 + scol,       &Bs[tid * 8]);
        gl_lds16(Wp + (size_t)(n0 + 64 + srow) * DIN + k0 + scol,  &Bs[2048 + tid * 8]);
        __syncthreads();
        bf16x8 af[4], bfr[4];
#pragma unroll
        for (int i = 0; i < 4; ++i)
            af[i] = *(const bf16x8*)(&As[(wm + i * 16 + lr16) * 32 + kq]);
#pragma unroll
        for (int j = 0; j < 4; ++j)
            bfr[j] = *(const bf16x8*)(&Bs[(wn + j * 16 + lr16) * 32 + kq]);
#pragma unroll
        for (int i = 0; i < 4; ++i)
#pragma unroll
            for (int j = 0; j < 4; ++j)
                acc[i][j] = __builtin_amdgcn_mfma_f32_16x16x32_bf16(af[i], bfr[j], acc[i][j], 0, 0, 0);
        __syncthreads();
    }
    const int crow = (lane >> 4) * 4, ccol = lane & 15;
#pragma unroll
    for (int i = 0; i < 4; ++i)
#pragma unroll
        for (int j = 0; j < 4; ++j)
#pragma unroll
            for (int r = 0; r < 4; ++r)
                Cs[(wm + i * 16 + crow + r) * 136 + wn + j * 16 + ccol] =
                    __float2bfloat16(acc[i][j][r]);
    __syncthreads();
#pragma unroll
    for (int p = 0; p < 8; ++p) {
        int row = p * 16 + (tid >> 4);
        int colg = (tid & 15) * 8;
        *(uint4*)(&Bu[(size_t)(m0 + row) * N1 + n0 + colg]) =
            *(const uint4*)(&Cs[row * 136 + colg]);
    }
}

// ---- scan phase 1 (R7 verbatim) ----
__global__ __launch_bounds__(512) void scan1(const bf16* __restrict__ Bu,
                                             const float* __restrict__ lam,
                                             float* __restrict__ Ssum) {
    int n = threadIdx.x;
    int c = blockIdx.x;
    int b = blockIdx.y;
    float lr = lam[n], li = lam[NST + n];
    const bf16* base = Bu + ((size_t)b * T_LEN + (size_t)c * CHL) * N1;
    float sr = 0.f, si = 0.f;
    for (int j = 0; j < CHL; ++j) {
        float br = __bfloat162float(base[(size_t)j * N1 + n]);
        float bi = __bfloat162float(base[(size_t)j * N1 + NST + n]);
        float tr = lr * sr - li * si + br;
        float ti = lr * si + li * sr + bi;
        sr = tr; si = ti;
    }
    size_t o = ((size_t)b * NCH + c) * N1 + n;
    Ssum[o] = sr; Ssum[o + NST] = si;
}

// ---- scan phase 3 with inline carry (R7 verbatim) ----
__global__ __launch_bounds__(512) void scan3(bf16* __restrict__ Bu,
                                             const float* __restrict__ lam,
                                             const float* __restrict__ lamL,
                                             const float* __restrict__ Ssum) {
    int n = threadIdx.x, c = blockIdx.x, b = blockIdx.y;
    float lr = lam[n], li = lam[NST + n];
    float Lr = lamL[n], Li = lamL[NST + n];
    float pr = 0.f, pi = 0.f;
    for (int cp = 0; cp < c; ++cp) {
        size_t o = ((size_t)b * NCH + cp) * N1 + n;
        float sr = Ssum[o], si = Ssum[o + NST];
        float tr = Lr * pr - Li * pi + sr;
        float ti = Lr * pi + Li * pr + si;
        pr = tr; pi = ti;
    }
    float xr = pr, xi = pi;
    bf16* base = Bu + ((size_t)b * T_LEN + (size_t)c * CHL) * N1;
    for (int j = 0; j < CHL; ++j) {
        float br = __bfloat162float(base[(size_t)j * N1 + n]);
        float bi = __bfloat162float(base[(size_t)j * N1 + NST + n]);
        float tr = lr * xr - li * xi + br;
        float ti = lr * xi + li * xr + bi;
        xr = tr; xi = ti;
        base[(size_t)j * N1 + n]       = __float2bfloat16(xr);
        base[(size_t)j * N1 + NST + n] = __float2bfloat16(xi);
    }
}

// ---- GEMM2: full-N block tile 128x256, 512 threads, 8 waves of 64x64 ----
// X (67 MB) now read exactly once; W2 fully reused per block; m97-ratio
// fragments (16 MFMA : 8 ds_read per wave-slice). Grid = 256 blocks.
__global__ __launch_bounds__(512) void gemm2(const bf16* __restrict__ X,
                                             const bf16* __restrict__ u,
                                             const bf16* __restrict__ W2,
                                             float* __restrict__ y) {
    __shared__ bf16 As[128 * 32];    // 8 KB
    __shared__ bf16 Bs[256 * 32];    // 16 KB
    const int tid = threadIdx.x;
    const int m0 = blockIdx.x * 128;
    const int lane = tid & 63, w = tid >> 6;
    const int wm = (w >> 2) * 64;    // {0,64}
    const int wn = (w & 3) * 64;     // {0,64,128,192}
    const int lr16 = lane & 15, kq = (lane >> 4) * 8;
    const int srow = tid >> 2;       // 0..127
    const int scol = (tid & 3) * 8;

    f32x4 acc[4][4] = {};
    for (int k0 = 0; k0 < K2; k0 += 32) {
        const bf16* Asrc; size_t lda; int kc;
        if (k0 < N1) { Asrc = X; lda = N1;  kc = k0; }
        else         { Asrc = u; lda = DIN; kc = k0 - N1; }
        gl_lds16(Asrc + (size_t)(m0 + srow) * lda + kc + scol,  &As[tid * 8]);
        gl_lds16(W2 + (size_t)srow * K2 + k0 + scol,            &Bs[tid * 8]);
        gl_lds16(W2 + (size_t)(128 + srow) * K2 + k0 + scol,    &Bs[4096 + tid * 8]);
        __syncthreads();
        bf16x8 af[4], bfr[4];
#pragma unroll
        for (int i = 0; i < 4; ++i)
            af[i] = *(const bf16x8*)(&As[(wm + i * 16 + lr16) * 32 + kq]);
#pragma unroll
        for (int j = 0; j < 4; ++j)
            bfr[j] = *(const bf16x8*)(&Bs[(wn + j * 16 + lr16) * 32 + kq]);
#pragma unroll
        for (int i = 0; i < 4; ++i)
#pragma unroll
            for (int j = 0; j < 4; ++j)
                acc[i][j] = __builtin_amdgcn_mfma_f32_16x16x32_bf16(af[i], bfr[j], acc[i][j], 0, 0, 0);
        __syncthreads();
    }
    const int crow = (lane >> 4) * 4, ccol = lane & 15;
#pragma unroll
    for (int i = 0; i < 4; ++i)
#pragma unroll
        for (int j = 0; j < 4; ++j)
#pragma unroll
            for (int r = 0; r < 4; ++r)
                y[(size_t)(m0 + wm + i * 16 + crow + r) * DOUT + wn + j * 16 + ccol] = acc[i][j][r];
}

extern "C" void kernel_launch(void* const* d_in, const int* in_sizes, int n_in,
                              void* d_out, int out_size, void* d_ws, size_t ws_size,
                              hipStream_t stream) {
    const float* u_in      = (const float*)d_in[0];
    const float* nu_log    = (const float*)d_in[1];
    const float* theta_log = (const float*)d_in[2];
    const float* gamma_log = (const float*)d_in[3];
    const float* B_real    = (const float*)d_in[4];
    const float* B_imag    = (const float*)d_in[5];
    const float* C_real    = (const float*)d_in[6];
    const float* C_imag    = (const float*)d_in[7];
    const float* Dm        = (const float*)d_in[8];
    float* y = (float*)d_out;
    char* ws = (char*)d_ws;

    bf16*  Bu   = (bf16*)ws;
    bf16*  u_bf = (bf16*)(ws + OFF_UBF);
    bf16*  Wp   = (bf16*)(ws + OFF_WP);
    bf16*  W2   = (bf16*)(ws + OFF_W2);
    float* lam  = (float*)(ws + OFF_LAM);
    float* lamL = (float*)(ws + OFF_LAML);
    float* Ssum = (float*)(ws + OFF_SSUM);

    prep<<<10496, 256, 0, stream>>>(u_in, nu_log, theta_log, gamma_log,
                                    B_real, B_imag, C_real, C_imag, Dm,
                                    u_bf, Wp, W2, lam, lamL);
    gemm1<<<dim3(M_ROWS / 128, N1 / 128), 256, 0, stream>>>(u_bf, Wp, Bu);
    scan1<<<dim3(NCH, B_SZ), 512, 0, stream>>>(Bu, lam, Ssum);
    scan3<<<dim3(NCH, B_SZ), 512, 0, stream>>>(Bu, lam, lamL, Ssum);
    gemm2<<<dim3(M_ROWS / 128), 512, 0, stream>>>(Bu, u_bf, W2, y);
}

// Round 10
// 202.597 us; speedup vs baseline: 1.3442x; 1.0195x over previous
//
#include <hip/hip_runtime.h>
#include <hip/hip_bf16.h>
#include <math.h>

#define B_SZ    8
#define T_LEN   4096
#define DIN     256
#define DOUT    256
#define NST     512
#define M_ROWS  (B_SZ * T_LEN)   // 32768
#define N1      (2 * NST)        // 1024: cols [0,512)=real plane, [512,1024)=imag plane
#define K2      (N1 + DIN)       // 1280
#define CHL     64               // scan chunk length
#define NCH     (T_LEN / CHL)    // 64

typedef __attribute__((ext_vector_type(8))) short bf16x8;
typedef __attribute__((ext_vector_type(4))) float f32x4;
typedef __hip_bfloat16 bf16;

// ws byte offsets
#define OFF_UBF  67108864
#define OFF_WP   83886080
#define OFF_W2   84410368
#define OFF_LAM  85065728
#define OFF_LAML 85069824
#define OFF_SSUM 85073920   // [B][NCH=64][N1] fp32 = 2 MB

__device__ __forceinline__ void gl_lds16(const bf16* g, bf16* l) {
    __builtin_amdgcn_global_load_lds(
        (const __attribute__((address_space(1))) void*)g,
        (__attribute__((address_space(3))) void*)l, 16, 0, 0);
}
__device__ __forceinline__ float bf_lo(unsigned w) {   // first bf16 (lower addr)
    union { unsigned u; float f; } c; c.u = w << 16; return c.f;
}
__device__ __forceinline__ float bf_hi(unsigned w) {   // second bf16
    union { unsigned u; float f; } c; c.u = w & 0xffff0000u; return c.f;
}
__device__ __forceinline__ unsigned bf_pack2(float a, float b) {  // [a,b] low,high
    union { bf16 h[2]; unsigned u; } p;
    p.h[0] = __float2bfloat16(a); p.h[1] = __float2bfloat16(b);
    return p.u;
}

// ---- prep: conv_u + pack_w1 + pack_w2, split-plane (lamL = lambda^64) ----
__global__ __launch_bounds__(256) void prep(const float* __restrict__ u,
        const float* __restrict__ nu_log, const float* __restrict__ theta_log,
        const float* __restrict__ gamma_log,
        const float* __restrict__ B_real, const float* __restrict__ B_imag,
        const float* __restrict__ C_real, const float* __restrict__ C_imag,
        const float* __restrict__ Dm,
        bf16* __restrict__ ub, bf16* __restrict__ Wp, bf16* __restrict__ W2,
        float* __restrict__ lam, float* __restrict__ lamL) {
    int bid = blockIdx.x, tid = threadIdx.x;
    if (bid < 8192) {                       // u -> bf16
        int i = bid * 256 + tid;
        float4 v = ((const float4*)u)[i];
        union { bf16 h[4]; uint2 u2; } p;
        p.h[0] = __float2bfloat16(v.x); p.h[1] = __float2bfloat16(v.y);
        p.h[2] = __float2bfloat16(v.z); p.h[3] = __float2bfloat16(v.w);
        ((uint2*)ub)[i] = p.u2;
    } else if (bid < 9216) {                // Wp (split planes) + lam/lamL
        int c = bid - 8192;                 // 0..1023
        int n = c & (NST - 1);
        float g = expf(gamma_log[n]);
        const float* src = (c < NST) ? (B_real + (size_t)n * DIN)
                                     : (B_imag + (size_t)n * DIN);
        Wp[(size_t)c * DIN + tid] = __float2bfloat16(g * src[tid]);
        int idx = c * 256 + tid;
        if (idx < NST) {
            float lm = expf(-expf(nu_log[idx]));
            float th = expf(theta_log[idx]);
            float lr = lm * cosf(th), li = lm * sinf(th);
            lam[idx] = lr; lam[NST + idx] = li;
            float ar = lr, ai = li;
#pragma unroll
            for (int q = 0; q < 6; ++q) {   // lambda^64 (CHL=64)
                float nr = ar * ar - ai * ai;
                float ni = 2.f * ar * ai;
                ar = nr; ai = ni;
            }
            lamL[idx] = ar; lamL[NST + idx] = ai;
        }
    } else {                                // W2 = [2Cr | -2Ci | D] split
        int idx = (bid - 9216) * 256 + tid;
        if (idx < DOUT * K2) {
            int o = idx / K2, c = idx - o * K2;
            float v;
            if (c < NST)            v =  2.0f * C_real[(size_t)o * NST + c];
            else if (c < 2 * NST)   v = -2.0f * C_imag[(size_t)o * NST + (c - NST)];
            else                    v =  Dm[(size_t)o * DIN + (c - 2 * NST)];
            W2[idx] = __float2bfloat16(v);
        }
    }
}

// ---- GEMM1 (R7 verbatim): LDS-packed coalesced Bu stores ----
__global__ __launch_bounds__(256) void gemm1(const bf16* __restrict__ u,
                                             const bf16* __restrict__ Wp,
                                             bf16* __restrict__ Bu) {
    __shared__ bf16 As[128 * 32];
    __shared__ bf16 Bs[128 * 32];
    __shared__ bf16 Cs[128 * 136];
    const int tid = threadIdx.x;
    const int m0 = blockIdx.x * 128, n0 = blockIdx.y * 128;
    const int lane = tid & 63, w = tid >> 6;
    const int wm = (w >> 1) * 64, wn = (w & 1) * 64;
    const int lr16 = lane & 15, kq = (lane >> 4) * 8;
    const int srow = tid >> 2, scol = (tid & 3) * 8;

    f32x4 acc[4][4] = {};
    for (int k0 = 0; k0 < DIN; k0 += 32) {
        gl_lds16(u  + (size_t)(m0 + srow) * DIN + k0 + scol,       &As[tid * 8]);
        gl_lds16(u  + (size_t)(m0 + 64 + srow) * DIN + k0 + scol,  &As[2048 + tid * 8]);
        gl_lds16(Wp + (size_t)(n0 + srow) * DIN + k0 + scol,       &Bs[tid * 8]);
        gl_lds16(Wp + (size_t)(n0 + 64 + srow) * DIN + k0 + scol,  &Bs[2048 + tid * 8]);
        __syncthreads();
        bf16x8 af[4], bfr[4];
#pragma unroll
        for (int i = 0; i < 4; ++i)
            af[i] = *(const bf16x8*)(&As[(wm + i * 16 + lr16) * 32 + kq]);
#pragma unroll
        for (int j = 0; j < 4; ++j)
            bfr[j] = *(const bf16x8*)(&Bs[(wn + j * 16 + lr16) * 32 + kq]);
#pragma unroll
        for (int i = 0; i < 4; ++i)
#pragma unroll
            for (int j = 0; j < 4; ++j)
                acc[i][j] = __builtin_amdgcn_mfma_f32_16x16x32_bf16(af[i], bfr[j], acc[i][j], 0, 0, 0);
        __syncthreads();
    }
    const int crow = (lane >> 4) * 4, ccol = lane & 15;
#pragma unroll
    for (int i = 0; i < 4; ++i)
#pragma unroll
        for (int j = 0; j < 4; ++j)
#pragma unroll
            for (int r = 0; r < 4; ++r)
                Cs[(wm + i * 16 + crow + r) * 136 + wn + j * 16 + ccol] =
                    __float2bfloat16(acc[i][j][r]);
    __syncthreads();
#pragma unroll
    for (int p = 0; p < 8; ++p) {
        int row = p * 16 + (tid >> 4);
        int colg = (tid & 15) * 8;
        *(uint4*)(&Bu[(size_t)(m0 + row) * N1 + n0 + colg]) =
            *(const uint4*)(&Cs[row * 136 + colg]);
    }
}

// ---- scan phase 1: paired states (2i,2i+1), dword loads, CHL=64 ----
__global__ __launch_bounds__(256) void scan1(const bf16* __restrict__ Bu,
                                             const float* __restrict__ lam,
                                             float* __restrict__ Ssum) {
    int i = threadIdx.x;            // 0..255, states 2i and 2i+1
    int c = blockIdx.x;             // 0..63
    int b = blockIdx.y;
    float2 lrp = *(const float2*)(lam + 2 * i);        // lam_r[2i], lam_r[2i+1]
    float2 lip = *(const float2*)(lam + NST + 2 * i);  // lam_i pair
    const bf16* base = Bu + ((size_t)b * T_LEN + (size_t)c * CHL) * N1;
    float sr0 = 0.f, si0 = 0.f, sr1 = 0.f, si1 = 0.f;
    for (int j = 0; j < CHL; ++j) {
        const unsigned* rp = (const unsigned*)(base + (size_t)j * N1);
        unsigned wr = rp[i];        // real cols 2i,2i+1
        unsigned wi = rp[256 + i];  // imag cols 512+2i,512+2i+1
        float br0 = bf_lo(wr), br1 = bf_hi(wr);
        float bi0 = bf_lo(wi), bi1 = bf_hi(wi);
        float t;
        t = lrp.x * sr0 - lip.x * si0 + br0; si0 = lrp.x * si0 + lip.x * sr0 + bi0; sr0 = t;
        t = lrp.y * sr1 - lip.y * si1 + br1; si1 = lrp.y * si1 + lip.y * sr1 + bi1; sr1 = t;
    }
    size_t o = ((size_t)b * NCH + c) * N1;
    *(float2*)(Ssum + o + 2 * i)       = make_float2(sr0, sr1);
    *(float2*)(Ssum + o + NST + 2 * i) = make_float2(si0, si1);
}

// ---- scan phase 3: inline carry + apply, paired states, dword ld/st ----
__global__ __launch_bounds__(256) void scan3(bf16* __restrict__ Bu,
                                             const float* __restrict__ lam,
                                             const float* __restrict__ lamL,
                                             const float* __restrict__ Ssum) {
    int i = threadIdx.x, c = blockIdx.x, b = blockIdx.y;
    float2 lrp = *(const float2*)(lam + 2 * i);
    float2 lip = *(const float2*)(lam + NST + 2 * i);
    float2 Lrp = *(const float2*)(lamL + 2 * i);
    float2 Lip = *(const float2*)(lamL + NST + 2 * i);
    float pr0 = 0.f, pi0 = 0.f, pr1 = 0.f, pi1 = 0.f;
    for (int cp = 0; cp < c; ++cp) {
        size_t o = ((size_t)b * NCH + cp) * N1;
        float2 s_r = *(const float2*)(Ssum + o + 2 * i);
        float2 s_i = *(const float2*)(Ssum + o + NST + 2 * i);
        float t;
        t = Lrp.x * pr0 - Lip.x * pi0 + s_r.x; pi0 = Lrp.x * pi0 + Lip.x * pr0 + s_i.x; pr0 = t;
        t = Lrp.y * pr1 - Lip.y * pi1 + s_r.y; pi1 = Lrp.y * pi1 + Lip.y * pr1 + s_i.y; pr1 = t;
    }
    float xr0 = pr0, xi0 = pi0, xr1 = pr1, xi1 = pi1;
    bf16* base = Bu + ((size_t)b * T_LEN + (size_t)c * CHL) * N1;
    for (int j = 0; j < CHL; ++j) {
        unsigned* rp = (unsigned*)(base + (size_t)j * N1);
        unsigned wr = rp[i];
        unsigned wi = rp[256 + i];
        float br0 = bf_lo(wr), br1 = bf_hi(wr);
        float bi0 = bf_lo(wi), bi1 = bf_hi(wi);
        float t;
        t = lrp.x * xr0 - lip.x * xi0 + br0; xi0 = lrp.x * xi0 + lip.x * xr0 + bi0; xr0 = t;
        t = lrp.y * xr1 - lip.y * xi1 + br1; xi1 = lrp.y * xi1 + lip.y * xr1 + bi1; xr1 = t;
        rp[i]       = bf_pack2(xr0, xr1);
        rp[256 + i] = bf_pack2(xi0, xi1);
    }
}

// ---- GEMM2 (R4-exact, best measured): y = [X | u_bf] @ W2^T,
//      128x128 tile, 512 threads, 2x4 waves of 64x32, grid (256,2) ----
__global__ __launch_bounds__(512) void gemm2(const bf16* __restrict__ X,
                                             const bf16* __restrict__ u,
                                             const bf16* __restrict__ W2,
                                             float* __restrict__ y) {
    __shared__ bf16 As[128 * 32];
    __shared__ bf16 Bs[128 * 32];
    const int tid = threadIdx.x;
    const int m0 = blockIdx.x * 128, n0 = blockIdx.y * 128;
    const int lane = tid & 63, w = tid >> 6;
    const int wm = (w >> 2) * 64, wn = (w & 3) * 32;
    const int lr16 = lane & 15, kq = (lane >> 4) * 8;
    const int srow = tid >> 2, scol = (tid & 3) * 8;

    f32x4 acc[4][2] = {};
    for (int k0 = 0; k0 < K2; k0 += 32) {
        const bf16* Asrc; size_t lda; int kc;
        if (k0 < N1) { Asrc = X; lda = N1;  kc = k0; }
        else         { Asrc = u; lda = DIN; kc = k0 - N1; }
        gl_lds16(Asrc + (size_t)(m0 + srow) * lda + kc + scol, &As[tid * 8]);
        gl_lds16(W2 + (size_t)(n0 + srow) * K2 + k0 + scol,    &Bs[tid * 8]);
        __syncthreads();
        bf16x8 af[4], bfr[2];
#pragma unroll
        for (int i = 0; i < 4; ++i)
            af[i] = *(const bf16x8*)(&As[(wm + i * 16 + lr16) * 32 + kq]);
#pragma unroll
        for (int j = 0; j < 2; ++j)
            bfr[j] = *(const bf16x8*)(&Bs[(wn + j * 16 + lr16) * 32 + kq]);
#pragma unroll
        for (int i = 0; i < 4; ++i)
#pragma unroll
            for (int j = 0; j < 2; ++j)
                acc[i][j] = __builtin_amdgcn_mfma_f32_16x16x32_bf16(af[i], bfr[j], acc[i][j], 0, 0, 0);
        __syncthreads();
    }
    const int crow = (lane >> 4) * 4, ccol = lane & 15;
#pragma unroll
    for (int i = 0; i < 4; ++i)
#pragma unroll
        for (int j = 0; j < 2; ++j)
#pragma unroll
            for (int r = 0; r < 4; ++r)
                y[(size_t)(m0 + wm + i * 16 + crow + r) * DOUT + n0 + wn + j * 16 + ccol] = acc[i][j][r];
}

extern "C" void kernel_launch(void* const* d_in, const int* in_sizes, int n_in,
                              void* d_out, int out_size, void* d_ws, size_t ws_size,
                              hipStream_t stream) {
    const float* u_in      = (const float*)d_in[0];
    const float* nu_log    = (const float*)d_in[1];
    const float* theta_log = (const float*)d_in[2];
    const float* gamma_log = (const float*)d_in[3];
    const float* B_real    = (const float*)d_in[4];
    const float* B_imag    = (const float*)d_in[5];
    const float* C_real    = (const float*)d_in[6];
    const float* C_imag    = (const float*)d_in[7];
    const float* Dm        = (const float*)d_in[8];
    float* y = (float*)d_out;
    char* ws = (char*)d_ws;

    bf16*  Bu   = (bf16*)ws;
    bf16*  u_bf = (bf16*)(ws + OFF_UBF);
    bf16*  Wp   = (bf16*)(ws + OFF_WP);
    bf16*  W2   = (bf16*)(ws + OFF_W2);
    float* lam  = (float*)(ws + OFF_LAM);
    float* lamL = (float*)(ws + OFF_LAML);
    float* Ssum = (float*)(ws + OFF_SSUM);

    prep<<<10496, 256, 0, stream>>>(u_in, nu_log, theta_log, gamma_log,
                                    B_real, B_imag, C_real, C_imag, Dm,
                                    u_bf, Wp, W2, lam, lamL);
    gemm1<<<dim3(M_ROWS / 128, N1 / 128), 256, 0, stream>>>(u_bf, Wp, Bu);
    scan1<<<dim3(NCH, B_SZ), 256, 0, stream>>>(Bu, lam, Ssum);
    scan3<<<dim3(NCH, B_SZ), 256, 0, stream>>>(Bu, lam, lamL, Ssum);
    gemm2<<<dim3(M_ROWS / 128, DOUT / 128), 512, 0, stream>>>(Bu, u_bf, W2, y);
}